// Round 6
// baseline (5491.578 us; speedup 1.0000x reference)
//
#include <hip/hip_runtime.h>
#include <hip/hip_fp16.h>

typedef _Float16 half8 __attribute__((ext_vector_type(8)));
typedef _Float16 half4v __attribute__((ext_vector_type(4)));
typedef float floatx4 __attribute__((ext_vector_type(4)));
typedef unsigned int uint;
typedef unsigned long long u64;

constexpr int BN = 128;    // batch
constexpr int T  = 1024;   // time steps
constexpr int D  = 512;    // input dim
constexpr int H  = 512;    // hidden dim

// Workspace layout (bytes)
constexpr size_t OFF_WIHT = 0;           // W_ih^T f16 = 512 KB
constexpr size_t OFF_WHHT = 524288;      // W_hh^T f16 = 512 KB
constexpr size_t OFF_HX   = 1048576;     // tagged h exchange: 2par*8grp*2half*2048 qwords = 512 KB
constexpr size_t OFF_XP   = 2097152;     // xp f16 [T][B][H] = 128 MB

__device__ __forceinline__ float fast_tanh(float x) {
    float e = __expf(2.0f * x);
    return 1.0f - 2.0f / (e + 1.0f);
}

struct U2 { uint lo, hi; };
struct U4 { uint x, y, z, w; };

__device__ __forceinline__ u64 pack_q(uint dataw, uint tag) {
    return (u64)dataw | ((u64)tag << 32);
}

// ---------------------------------------------------------------------------
// Prep: transpose 512x512 fp32 -> fp16 (row-major [n][k] = W[k][n]).
// Also zeroes the 512 KB tagged-exchange region every launch (tags reset to 0
// so a stale tag from a previous replay can never equal a live step tag).
// Kernel-boundary release makes the zeros visible to rnn_scan (R2-proven).
// ---------------------------------------------------------------------------
__global__ __launch_bounds__(256) void prep_transpose(
    const float* __restrict__ Wih, const float* __restrict__ Whh,
    _Float16* __restrict__ WihT, _Float16* __restrict__ WhhT,
    u64* __restrict__ hxq)
{
    if (blockIdx.z == 0) {
        const int bi = blockIdx.y * 16 + blockIdx.x;      // 0..255
        hxq[(size_t)bi * 256 + threadIdx.x] = 0ULL;       // 256*256 = 65536 qwords
    }

    __shared__ float tile[32][33];
    const float* src = (blockIdx.z == 0) ? Wih : Whh;
    _Float16* dst    = (blockIdx.z == 0) ? WihT : WhhT;
    const int tx = threadIdx.x & 31;
    const int ty = threadIdx.x >> 5;
    const int kbase = blockIdx.y * 32;
    const int nbase = blockIdx.x * 32;
    for (int r = 0; r < 4; ++r)
        tile[ty + r * 8][tx] = src[(size_t)(kbase + ty + r * 8) * 512 + nbase + tx];
    __syncthreads();
    for (int r = 0; r < 4; ++r)
        dst[(size_t)(nbase + ty + r * 8) * 512 + kbase + tx] =
            (_Float16)tile[tx][ty + r * 8];
}

// ---------------------------------------------------------------------------
// Phase 1: xp[t][b][n] = x[b][t][:] @ W_ih + bias   (fp16 out, bias folded)
// ---------------------------------------------------------------------------
__global__ __launch_bounds__(256) void xp_gemm(
    const float* __restrict__ x, const _Float16* __restrict__ WT,
    const float* __restrict__ bias, _Float16* __restrict__ xp)
{
    __shared__ _Float16 As[128][40];
    __shared__ _Float16 Bs[128][40];
    const int tid  = threadIdx.x;
    const int lane = tid & 63;
    const int w    = tid >> 6;
    const int wm   = w & 1, wn = w >> 1;
    const int l15  = lane & 15, q = lane >> 4;
    const size_t mbase = (size_t)blockIdx.y * 128;
    const int    nbase = blockIdx.x * 128;

    floatx4 acc[4][4];
    for (int i = 0; i < 4; ++i)
        for (int j = 0; j < 4; ++j)
            acc[i][j] = (floatx4){0.f, 0.f, 0.f, 0.f};

    for (int kt = 0; kt < 16; ++kt) {
        const int k0 = kt * 32;
        {
            const int k4 = (tid & 7) * 4;
            const int row0 = tid >> 3;
            for (int r = 0; r < 4; ++r) {
                const int row = row0 + r * 32;
                const float4 v = *(const float4*)&x[(mbase + row) * D + k0 + k4];
                half4v hv;
                hv[0] = (_Float16)v.x; hv[1] = (_Float16)v.y;
                hv[2] = (_Float16)v.z; hv[3] = (_Float16)v.w;
                *(half4v*)&As[row][k4] = hv;
            }
        }
        {
            const int k8 = (tid & 3) * 8;
            const int n0 = tid >> 2;
            for (int r = 0; r < 2; ++r) {
                const int n = n0 + r * 64;
                *(half8*)&Bs[n][k8] =
                    *(const half8*)&WT[(size_t)(nbase + n) * D + k0 + k8];
            }
        }
        __syncthreads();
        half8 a[4], b[4];
        for (int i = 0; i < 4; ++i)
            a[i] = *(const half8*)&As[wm * 64 + i * 16 + l15][q * 8];
        for (int j = 0; j < 4; ++j)
            b[j] = *(const half8*)&Bs[wn * 64 + j * 16 + l15][q * 8];
        for (int i = 0; i < 4; ++i)
            for (int j = 0; j < 4; ++j)
                acc[i][j] = __builtin_amdgcn_mfma_f32_16x16x32_f16(
                    a[i], b[j], acc[i][j], 0, 0, 0);
        __syncthreads();
    }
    float bc[4];
    for (int j = 0; j < 4; ++j)
        bc[j] = bias[nbase + wn * 64 + j * 16 + l15];
    for (int i = 0; i < 4; ++i)
        for (int r = 0; r < 4; ++r) {
            const size_t row = mbase + wm * 64 + i * 16 + q * 4 + r;
            const int b_row = (int)(row >> 10);      // T = 1024
            const int tt    = (int)(row & 1023);
            _Float16* dst = &xp[((size_t)tt * BN + b_row) * H];
            for (int j = 0; j < 4; ++j) {
                const int col = nbase + wn * 64 + j * 16 + l15;
                dst[col] = (_Float16)(acc[i][j][r] + bc[j]);
            }
        }
}

// ---------------------------------------------------------------------------
// Tagged publish: 4 halves -> 2 qwords, each {2xf16 payload | 32b step tag}.
// Agent-relaxed 64b atomics (R1/R2-proven primitive). Tag+payload in ONE
// atom: the consumer's passing tag check certifies the payload of the same
// load — no drain, no flag, no fence anywhere. Fire-and-forget.
// ---------------------------------------------------------------------------
__device__ __forceinline__ void publish_own(u64* base, int eq,
                                            half4v hn0, half4v hn1, uint tag)
{
    const U2 a = __builtin_bit_cast(U2, hn0);
    const U2 b = __builtin_bit_cast(U2, hn1);
    __hip_atomic_store(&base[eq + 0],   pack_q(a.lo, tag),
                       __ATOMIC_RELAXED, __HIP_MEMORY_SCOPE_AGENT);
    __hip_atomic_store(&base[eq + 1],   pack_q(a.hi, tag),
                       __ATOMIC_RELAXED, __HIP_MEMORY_SCOPE_AGENT);
    __hip_atomic_store(&base[eq + 128], pack_q(b.lo, tag),
                       __ATOMIC_RELAXED, __HIP_MEMORY_SCOPE_AGENT);
    __hip_atomic_store(&base[eq + 129], pack_q(b.hi, tag),
                       __ATOMIC_RELAXED, __HIP_MEMORY_SCOPE_AGENT);
}

// Poll all 8 peer k-chunks (32 qwords, one latency) until every tag == want.
// BOUNDED: 1024 retries (~400us) then proceed — a broken sync produces a
// wrong-answer bench WITH counters instead of a dead container.
__device__ __forceinline__ void poll32(const u64* __restrict__ pr, int qb,
                                       uint want, half8* dst)
{
    u64 v[32];
    for (int it = 0; it < 1024; ++it) {
#pragma unroll
        for (int c = 0; c < 8; ++c)
#pragma unroll
            for (int j = 0; j < 4; ++j)
                v[c * 4 + j] = __hip_atomic_load(&pr[c * 256 + qb + j],
                               __ATOMIC_RELAXED, __HIP_MEMORY_SCOPE_AGENT);
        uint bad = 0;
#pragma unroll
        for (int k = 0; k < 32; ++k)
            bad |= ((uint)(v[k] >> 32)) ^ want;
        if (!__any(bad != 0)) break;
        __builtin_amdgcn_s_sleep(2);
    }
#pragma unroll
    for (int c = 0; c < 8; ++c) {
        const U4 d = { (uint)v[c * 4 + 0], (uint)v[c * 4 + 1],
                       (uint)v[c * 4 + 2], (uint)v[c * 4 + 3] };
        dst[c] = __builtin_bit_cast(half8, d);
    }
}

// ---------------------------------------------------------------------------
// Phase 2: sequential scan, H-split across 16 CUs, tagged-data exchange.
// Block (g, half): 16 batch rows, 256 output cols. W slice all in AGPRs.
// Per step: phase1 (own half, LDS) || peer data in flight -> poll (tag==t)
// -> phase2 -> tanh -> publish (fire-and-forget tagged stores) -> LDS own
// half -> lgkmcnt-only raw barrier (publish stores stay in flight; the
// consumer's tag check orders them, not the barrier).
// Pairwise lockstep is self-enforcing (publish t+1 only after consuming t);
// 2-parity slots prevent overwrite; prep's zeroing kills cross-replay tags.
// ---------------------------------------------------------------------------
__global__ __launch_bounds__(512, 2) void rnn_scan(
    const _Float16* __restrict__ xp, const _Float16* __restrict__ WT,
    float* __restrict__ out, u64* __restrict__ hxq)
{
    __shared__ _Float16 hbuf[2][4096];   // 16 KB: own 256-col half, frag order

    const int bid  = blockIdx.x;        // 0..15
    const int half = bid >> 3;          // output column half
    const int g    = bid & 7;           // batch group
    const int tid  = threadIdx.x;
    const int lane = tid & 63;
    const int w    = tid >> 6;          // wave 0..7
    const int l15  = lane & 15;
    const int q    = lane >> 4;

    // W^T rows for this wave's two 16-col m-tiles
    const int nbase = half * 256 + w * 32;
    const _Float16* wr0 = WT + (size_t)(nbase + 0  + l15) * H + q * 8;
    const _Float16* wr1 = WT + (size_t)(nbase + 16 + l15) * H + q * 8;

    // Whole W slice in AGPRs: j=0..7 own-half k-chunks, j=8..15 peer-half
    half8 wa[16][2];
#pragma unroll
    for (int j = 0; j < 16; ++j) {
        const int c = (j < 8) ? (half * 8 + j) : ((half ^ 1) * 8 + (j - 8));
        wa[j][0] = *(const half8*)&wr0[c * 32];
        wa[j][1] = *(const half8*)&wr1[c * 32];
        asm volatile("" : "+a"(wa[j][0]), "+a"(wa[j][1]));
    }

    // own-fragment write base (halves, within a 4096-half region) + qword base
    const int ebase = ((w * 4 + (q >> 1)) * 16 + l15) * 8 + (q & 1) * 4;
    const int eq    = ebase >> 1;
    // consumer lane qword base within a region
    const int qb    = q * 64 + l15 * 4;

    // region bases (qwords; region = 2048 qwords = 4096 halves tagged)
    u64* own0 = hxq + ((size_t)(0 * 8 + g) * 2 + half) * 2048;
    u64* own1 = hxq + ((size_t)(1 * 8 + g) * 2 + half) * 2048;
    const u64* peer0 = hxq + ((size_t)(0 * 8 + g) * 2 + (half ^ 1)) * 2048;
    const u64* peer1 = hxq + ((size_t)(1 * 8 + g) * 2 + (half ^ 1)) * 2048;

    // ---- t = 0: h1(own half) = tanh(xp_0); publish tagged 1; LDS; barrier
    {
        const _Float16* x0 = xp + ((size_t)g * 16 + l15) * H + nbase + q * 4;
        half4v v0 = *(const half4v*)&x0[0];
        half4v v1 = *(const half4v*)&x0[16];
        half4v hn0, hn1;
#pragma unroll
        for (int r = 0; r < 4; ++r) {
            hn0[r] = (_Float16)fast_tanh((float)v0[r]);
            hn1[r] = (_Float16)fast_tanh((float)v1[r]);
        }
        publish_own(own1, eq, hn0, hn1, 1u);
        *(half4v*)&hbuf[1][ebase]       = hn0;
        *(half4v*)&hbuf[1][ebase + 256] = hn1;
        __syncthreads();
    }

    const _Float16* xlane = xp + ((size_t)g * 16 + l15) * H + nbase + q * 4;

    for (int t = 1; t < T; ++t) {
        // xp prefetch (independent of h)
        const _Float16* xt = xlane + (size_t)t * (BN * H);
        const half4v xpv0 = *(const half4v*)&xt[0];
        const half4v xpv1 = *(const half4v*)&xt[16];

        // phase 1: own-half k-chunks from LDS
        const _Float16* hbo = &hbuf[t & 1][(q * 16 + l15) * 8];
        half8 hfA[8];
#pragma unroll
        for (int c8 = 0; c8 < 8; ++c8)
            hfA[c8] = *(const half8*)&hbo[c8 * 512];
        floatx4 acc0 = (floatx4){0.f,0.f,0.f,0.f};
        floatx4 acc1 = (floatx4){0.f,0.f,0.f,0.f};
#pragma unroll
        for (int c8 = 0; c8 < 8; ++c8) {
            acc0 = __builtin_amdgcn_mfma_f32_16x16x32_f16(wa[c8][0], hfA[c8], acc0, 0, 0, 0);
            acc1 = __builtin_amdgcn_mfma_f32_16x16x32_f16(wa[c8][1], hfA[c8], acc1, 0, 0, 0);
        }

        // poll peer's tagged h_t (tag == t certifies payload of same load)
        const u64* pr = (t & 1) ? peer1 : peer0;
        half8 hfB[8];
        poll32(pr, qb, (uint)t, hfB);

        // phase 2: peer-half k-chunks
#pragma unroll
        for (int c8 = 0; c8 < 8; ++c8) {
            acc0 = __builtin_amdgcn_mfma_f32_16x16x32_f16(wa[8 + c8][0], hfB[c8], acc0, 0, 0, 0);
            acc1 = __builtin_amdgcn_mfma_f32_16x16x32_f16(wa[8 + c8][1], hfB[c8], acc1, 0, 0, 0);
        }

        // tanh + publish (fire-and-forget) + own-half LDS + raw barrier
        if (t < T - 1) {
            half4v hn0, hn1;
#pragma unroll
            for (int r = 0; r < 4; ++r) {
                hn0[r] = (_Float16)fast_tanh(acc0[r] + (float)xpv0[r]);
                hn1[r] = (_Float16)fast_tanh(acc1[r] + (float)xpv1[r]);
            }
            publish_own(((t + 1) & 1) ? own1 : own0, eq, hn0, hn1, (uint)(t + 1));
            _Float16* ho = hbuf[(t + 1) & 1];
            *(half4v*)&ho[ebase]       = hn0;
            *(half4v*)&ho[ebase + 256] = hn1;
            // LDS-only barrier: do NOT drain vmcnt (publish stores stay in
            // flight; consumer's tag check orders them, not this barrier).
            asm volatile("s_waitcnt lgkmcnt(0)" ::: "memory");
            __builtin_amdgcn_sched_barrier(0);
            __builtin_amdgcn_s_barrier();
            __builtin_amdgcn_sched_barrier(0);
        } else {
            float4 o0, o1;
            o0.x = fast_tanh(acc0[0] + (float)xpv0[0]);
            o0.y = fast_tanh(acc0[1] + (float)xpv0[1]);
            o0.z = fast_tanh(acc0[2] + (float)xpv0[2]);
            o0.w = fast_tanh(acc0[3] + (float)xpv0[3]);
            o1.x = fast_tanh(acc1[0] + (float)xpv1[0]);
            o1.y = fast_tanh(acc1[1] + (float)xpv1[1]);
            o1.z = fast_tanh(acc1[2] + (float)xpv1[2]);
            o1.w = fast_tanh(acc1[3] + (float)xpv1[3]);
            float* ob = &out[((size_t)g * 16 + l15) * H + nbase + q * 4];
            *(float4*)&ob[0]  = o0;
            *(float4*)&ob[16] = o1;
        }
    }
}

// ---------------------------------------------------------------------------
extern "C" void kernel_launch(void* const* d_in, const int* in_sizes, int n_in,
                              void* d_out, int out_size, void* d_ws, size_t ws_size,
                              hipStream_t stream)
{
    const float* x   = (const float*)d_in[0];
    const float* Wih = (const float*)d_in[1];
    const float* Whh = (const float*)d_in[2];
    const float* b   = (const float*)d_in[3];
    float* out = (float*)d_out;

    char* ws = (char*)d_ws;
    _Float16* WihT = (_Float16*)(ws + OFF_WIHT);
    _Float16* WhhT = (_Float16*)(ws + OFF_WHHT);
    u64*      hxq  = (u64*)(ws + OFF_HX);
    _Float16* xp   = (_Float16*)(ws + OFF_XP);

    prep_transpose<<<dim3(16, 16, 2), 256, 0, stream>>>(Wih, Whh, WihT, WhhT, hxq);
    xp_gemm<<<dim3(4, 1024), 256, 0, stream>>>(x, WihT, b, xp);
    rnn_scan<<<16, 512, 0, stream>>>(xp, WhhT, out, hxq);
}